// Round 2
// baseline (1371.091 us; speedup 1.0000x reference)
//
#include <hip/hip_runtime.h>
#include <cstdint>
#include <cstddef>

typedef __bf16 bf16x8 __attribute__((ext_vector_type(8)));
typedef __bf16 bf16x4 __attribute__((ext_vector_type(4)));
typedef float  f32x4  __attribute__((ext_vector_type(4)));

#define MFMA16(a,b,c) __builtin_amdgcn_mfma_f32_16x16x32_bf16((a),(b),(c),0,0,0)

// Problem constants: B=256, T=512, D=H=128, 3H=384.
// x row stride (b): T*D = 65536 elems. out row stride (b): T*H = 65536 elems.

// ---------------------------------------------------------------------------
// prep_frags: build MFMA B-operand frag-ordered weight arrays.
// Frag layout (16x16x32 bf16): B[k][n], n = lane&15, k = kt*32 + (lane>>4)*8 + j
// Array elem offset = ((ct*4+kt)*64 + lane)*8 + j, ct in 0..23, kt in 0..3.
// Outputs (each 49152 bf16): [0]=W0hi [1]=W0lo [2]=U0 [3]=W1hi [4]=W1lo [5]=U1
// (hi/lo split only for W; U used single-bf16.)
// ---------------------------------------------------------------------------
__global__ void prep_frags(const float* __restrict__ W0, const float* __restrict__ U0,
                           const float* __restrict__ W1, const float* __restrict__ U1,
                           __bf16* __restrict__ frags)
{
    int id = blockIdx.x * 512 + threadIdx.x;      // 0..24575
    int mat = id / 6144;                          // 0..3 : W0,U0,W1,U1
    int r   = id % 6144;                          // (ct*4+kt)*64 + lane
    int lane = r & 63;
    int ctkt = r >> 6;                            // 0..95
    int kt = ctkt & 3;
    int ct = ctkt >> 2;
    const float* src = (mat == 0) ? W0 : (mat == 1) ? U0 : (mat == 2) ? W1 : U1;
    int n  = ct * 16 + (lane & 15);
    int k0 = kt * 32 + (lane >> 4) * 8;
    __bf16 hi[8], lo[8];
#pragma unroll
    for (int j = 0; j < 8; j++) {
        float v = src[(size_t)(k0 + j) * 384 + n];
        __bf16 h = (__bf16)v;
        hi[j] = h;
        lo[j] = (__bf16)(v - (float)h);
    }
    int hiArr = (mat == 0) ? 0 : (mat == 1) ? 2 : (mat == 2) ? 3 : 5;
    __bf16* dhi = frags + (size_t)hiArr * 49152 + (size_t)r * 8;
#pragma unroll
    for (int j = 0; j < 8; j++) dhi[j] = hi[j];
    if (mat == 0 || mat == 2) {
        __bf16* dlo = frags + (size_t)(hiArr + 1) * 49152 + (size_t)r * 8;
#pragma unroll
        for (int j = 0; j < 8; j++) dlo[j] = lo[j];
    }
}

// ---------------------------------------------------------------------------
// gru_fused: one GRU layer, input projection fused into the scan.
// 16 blocks x 512 threads (8 waves); block handles 16 batch rows, T=512 steps.
// Wave w owns output col-tiles {w (z), w+8 (r), w+16 (h)}; lane: col j=16w+l15,
// batch rows quad*4+reg (C layout: col=lane&15, row=quad*4+reg).
// Per step: A-frags of x_t (hi/lo) and h_{t-1} (bf16) read from LDS
// (A layout: m=lane&15, k=quad*8+j within each kt*32 slab);
// xp = 3-product (xh*Wh + xl*Wh + xh*Wl) => ~fp32; rec = single bf16.
// Double-buffered LDS -> ONE barrier per step.
// xin may alias hout (in-place layer 1): block reads x[b,t] strictly before
// writing hout[b,t]; blocks own disjoint batch rows. No __restrict__ on these.
// ---------------------------------------------------------------------------
__global__ __launch_bounds__(512) void gru_fused(
    const float* xin, const __bf16* __restrict__ Uf,
    const __bf16* __restrict__ Wh, const __bf16* __restrict__ Wl,
    const float* __restrict__ bias, float* hout)
{
    __shared__ __align__(16) __bf16 xbh[2][16 * 136];
    __shared__ __align__(16) __bf16 xbl[2][16 * 136];
    __shared__ __align__(16) __bf16 hbuf[2][16 * 136];

    const int tid = threadIdx.x;
    const int wave = tid >> 6, lane = tid & 63;
    const int l15 = lane & 15, quad = lane >> 4;
    const int B0 = blockIdx.x * 16;

    // persistent B-frags in VGPRs: 36 frags = 144 VGPRs
    bf16x8 uf[3][4], wh[3][4], wl[3][4];
#pragma unroll
    for (int g = 0; g < 3; g++) {
        int ct = wave + 8 * g;
#pragma unroll
        for (int kt = 0; kt < 4; kt++) {
            size_t off = (size_t)((ct * 4 + kt) * 64 + lane) * 8;
            uf[g][kt] = *(const bf16x8*)(Uf + off);
            wh[g][kt] = *(const bf16x8*)(Wh + off);
            wl[g][kt] = *(const bf16x8*)(Wl + off);
        }
    }

    const int j = wave * 16 + l15;                  // hidden index 0..127
    const float bcz  = bias[j]       + bias[384 + j];        // b_in_z + b_rec_z
    const float bcr  = bias[128 + j] + bias[512 + j];        // b_in_r + b_rec_r
    const float binh = bias[256 + j];
    const float brh  = bias[640 + j];

    // staging addressing (tid-based): row = batch-local 0..15, 4 floats/thread
    const int srow = tid >> 5;
    const int scol = (tid & 31) * 4;
    const float* px = xin + (size_t)(B0 + srow) * 65536 + scol;
    const int sidx = srow * 136 + scol;

    float* ho[4];
#pragma unroll
    for (int r = 0; r < 4; r++)
        ho[r] = hout + (size_t)(B0 + quad * 4 + r) * 65536 + j;

    // prologue: stage x_0 into buffer 0, zero h buffer 0
    {
        float4 v = *(const float4*)px;
        bf16x4 hv, lv;
        hv.x = (__bf16)v.x; lv.x = (__bf16)(v.x - (float)hv.x);
        hv.y = (__bf16)v.y; lv.y = (__bf16)(v.y - (float)hv.y);
        hv.z = (__bf16)v.z; lv.z = (__bf16)(v.z - (float)hv.z);
        hv.w = (__bf16)v.w; lv.w = (__bf16)(v.w - (float)hv.w);
        *(bf16x4*)&xbh[0][sidx] = hv;
        *(bf16x4*)&xbl[0][sidx] = lv;
    }
    if (tid < 272) ((uint4*)&hbuf[0][0])[tid] = make_uint4(0, 0, 0, 0);
    __syncthreads();

    float hold[4] = {0.f, 0.f, 0.f, 0.f};
    const int abase = l15 * 136 + quad * 8;

    for (int t = 0; t < 512; t++) {
        const int cur = t & 1, nxt = cur ^ 1;
        const int tn = (t < 511) ? (t + 1) : 511;   // clamped prefetch
        float4 v = *(const float4*)(px + (size_t)tn * 128);

        f32x4 az = {0,0,0,0}, arr = {0,0,0,0}, ahh = {0,0,0,0};
        f32x4 xz = {0,0,0,0}, xr  = {0,0,0,0}, xh  = {0,0,0,0};
#pragma unroll
        for (int kt = 0; kt < 4; kt++) {
            bf16x8 hA = *(const bf16x8*)&hbuf[cur][abase + kt * 32];
            bf16x8 xH = *(const bf16x8*)&xbh[cur][abase + kt * 32];
            bf16x8 xL = *(const bf16x8*)&xbl[cur][abase + kt * 32];
            az  = MFMA16(hA, uf[0][kt], az);
            arr = MFMA16(hA, uf[1][kt], arr);
            ahh = MFMA16(hA, uf[2][kt], ahh);
            xz  = MFMA16(xH, wh[0][kt], xz);
            xr  = MFMA16(xH, wh[1][kt], xr);
            xh  = MFMA16(xH, wh[2][kt], xh);
            xz  = MFMA16(xL, wh[0][kt], xz);
            xr  = MFMA16(xL, wh[1][kt], xr);
            xh  = MFMA16(xL, wh[2][kt], xh);
            xz  = MFMA16(xH, wl[0][kt], xz);
            xr  = MFMA16(xH, wl[1][kt], xr);
            xh  = MFMA16(xH, wl[2][kt], xh);
        }

        float hnew[4];
#pragma unroll
        for (int r = 0; r < 4; r++) {
            float zp = az[r]  + xz[r] + bcz;
            float rp = arr[r] + xr[r] + bcr;
            float z  = __builtin_amdgcn_rcpf(1.f + __expf(-zp));
            float rg = __builtin_amdgcn_rcpf(1.f + __expf(-rp));
            float hp = (xh[r] + binh) + rg * (ahh[r] + brh);
            float e2 = __expf(2.f * hp);
            float th = 1.f - 2.f * __builtin_amdgcn_rcpf(e2 + 1.f);
            hnew[r] = th + z * (hold[r] - th);
            hold[r] = hnew[r];
        }

        // write NEXT buffers (double-buffered: no WAR with current readers)
        {
            bf16x4 hv, lv;
            hv.x = (__bf16)v.x; lv.x = (__bf16)(v.x - (float)hv.x);
            hv.y = (__bf16)v.y; lv.y = (__bf16)(v.y - (float)hv.y);
            hv.z = (__bf16)v.z; lv.z = (__bf16)(v.z - (float)hv.z);
            hv.w = (__bf16)v.w; lv.w = (__bf16)(v.w - (float)hv.w);
            *(bf16x4*)&xbh[nxt][sidx] = hv;
            *(bf16x4*)&xbl[nxt][sidx] = lv;
        }
#pragma unroll
        for (int r = 0; r < 4; r++)
            hbuf[nxt][(quad * 4 + r) * 136 + j] = (__bf16)hnew[r];

        __syncthreads();   // single barrier: t+1 buffers visible to all

        // h_t stores drain during next step's compute
#pragma unroll
        for (int r = 0; r < 4; r++)
            ho[r][(size_t)t * 128] = hnew[r];
    }
}

// ---------------------------------------------------------------------------
extern "C" void kernel_launch(void* const* d_in, const int* in_sizes, int n_in,
                              void* d_out, int out_size, void* d_ws, size_t ws_size,
                              hipStream_t stream)
{
    const float* x  = (const float*)d_in[0];
    const float* W0 = (const float*)d_in[1];
    const float* U0 = (const float*)d_in[2];
    const float* b0 = (const float*)d_in[3];
    const float* W1 = (const float*)d_in[4];
    const float* U1 = (const float*)d_in[5];
    const float* b1 = (const float*)d_in[6];
    float* out = (float*)d_out;

    char* ws = (char*)d_ws;
    __bf16* frags = (__bf16*)ws;                 // 6 * 49152 bf16 = 589,824 B
    const __bf16* W0hi = frags;
    const __bf16* W0lo = frags + 49152;
    const __bf16* U0f  = frags + 2 * 49152;
    const __bf16* W1hi = frags + 3 * 49152;
    const __bf16* W1lo = frags + 4 * 49152;
    const __bf16* U1f  = frags + 5 * 49152;

    // h0 (layer-0 output, 67,108,864 B): use ws if it fits, else run layer 1
    // in-place through d_out (gru_fused is alias-safe).
    float* h0;
    const size_t need = 589824 + 67108864;       // frags + h0
    if (ws_size >= need) h0 = (float*)(ws + 589824);
    else                 h0 = out;

    prep_frags<<<48, 512, 0, stream>>>(W0, U0, W1, U1, frags);
    gru_fused<<<16, 512, 0, stream>>>(x,  U0f, W0hi, W0lo, b0, h0);
    gru_fused<<<16, 512, 0, stream>>>(h0, U1f, W1hi, W1lo, b1, out);
}